// Round 6
// baseline (295.338 us; speedup 1.0000x reference)
//
#include <hip/hip_runtime.h>
#include <hip/hip_bf16.h>

// TransformerBlock: B=8,S=196,D=768,H=12,HD=64,E=8,FF=3072. T = B*S = 1568 tokens.
//
// Exact simplifications:
//  - attention: k,v broadcast across heads -> logits constant over softmax axis
//    -> softmax uniform -> attn_out = tile(v). Wq/bq/Wk/bk/RoPE are dead code.
//  - MoE top-1 = argmax of gating logits (softmax monotone).
//
// R7 structure (= R6 + vproj precision fix):
//  - R6 FAILED (absmax 1.6): vproj rounded Wv to bf16 -> v perturbed ~4e-3 ->
//    gate argmax flipped on near-tie tokens -> O(1) output error. The gate
//    input path must keep Wv at ~fp32 precision (R0-R4 proven).
//  - k_vproj now uses SPLIT-PRECISION B: Wv = hi + lo (both bf16), two LDS
//    buffers, acc = mfma(A,hi)+mfma(A,lo)  => B error ~2^-16 (fp32-like).
//    h1 stays bf16 (proven safe in R0).
//  - Front: k_ln1 (1 wave/token), k_vproj (MFMA GEMM, 25 blocks), k_gate.
//  - MoE GEMMs: BM=64 (2x active blocks ~6/CU), A DIRECT TO REGISTERS
//    (wave-exclusive strip, no A LDS staging), B staged via LDS, depth-2
//    register prefetch, raw s_barrier (no vmcnt drain).
//  - GEMM2 split-K x4 atomicAdds onto out pre-initialized with x2 + b2[expert].

typedef unsigned short u16;
typedef short bf16x8_t __attribute__((ext_vector_type(8)));
typedef unsigned short u16x4_t __attribute__((ext_vector_type(4)));
typedef float f32x4_t  __attribute__((ext_vector_type(4)));

#define T_TOK 1568
#define DM 768
#define HD 64
#define FF 3072
#define NE 8

// workspace layout (16B-aligned offsets; ~14.9 MB total)
#define OFF_CNT   0
#define OFF_BUCK  256
#define OFF_V     (OFF_BUCK + NE*T_TOK*4)
#define OFF_H1    (OFF_V + T_TOK*HD*4)
#define OFF_H2    (OFF_H1 + T_TOK*DM*2)
#define OFF_HMID  (OFF_H2 + T_TOK*DM*2)

__device__ __forceinline__ u16 f2bf(float f) {  // RNE via HW cvt
    return __builtin_bit_cast(u16, __float2bfloat16(f));
}
__device__ __forceinline__ float bf2f(u16 h) {
    unsigned u = ((unsigned)h) << 16;
    return __builtin_bit_cast(float, u);
}
__device__ __forceinline__ float gelu_f(float x) {
    return 0.5f * x * (1.0f + erff(x * 0.70710678118654752440f));
}

#define SFENCE() __builtin_amdgcn_sched_barrier(0)
#define RAW_BAR() __builtin_amdgcn_s_barrier()

// ---------------- K1: LN1 per token -> h1 (bf16), 1 wave/token ----------------
__global__ __launch_bounds__(64) void k_ln1(const float* __restrict__ x,
                                            const float* __restrict__ g1,
                                            const float* __restrict__ b1,
                                            u16* __restrict__ h1) {
    int t = blockIdx.x, lane = threadIdx.x;
    const float* xp = x + (size_t)t * DM;
    f32x4_t xv[3];
    float s = 0.0f;
#pragma unroll
    for (int i = 0; i < 3; i++) {
        xv[i] = *(const f32x4_t*)&xp[4 * lane + 256 * i];
        s += xv[i][0] + xv[i][1] + xv[i][2] + xv[i][3];
    }
#pragma unroll
    for (int m = 1; m < 64; m <<= 1) s += __shfl_xor(s, m);
    float mu = s * (1.0f / DM);
    float vs = 0.0f;
#pragma unroll
    for (int i = 0; i < 3; i++)
#pragma unroll
        for (int m = 0; m < 4; m++) { float d = xv[i][m] - mu; vs += d * d; }
#pragma unroll
    for (int m = 1; m < 64; m <<= 1) vs += __shfl_xor(vs, m);
    float rs = rsqrtf(vs * (1.0f / DM) + 1e-5f);
    u16* hp = h1 + (size_t)t * DM;
#pragma unroll
    for (int i = 0; i < 3; i++) {
        int c = 4 * lane + 256 * i;
        f32x4_t gg = *(const f32x4_t*)&g1[c];
        f32x4_t bb = *(const f32x4_t*)&b1[c];
        u16x4_t hb;
#pragma unroll
        for (int m = 0; m < 4; m++) hb[m] = f2bf((xv[i][m] - mu) * rs * gg[m] + bb[m]);
        *(u16x4_t*)&hp[c] = hb;
    }
}

// ---------------- K2: vproj GEMM: v = h1[1568,768] @ Wv[768,64] + bv ----------------
// 25 blocks x 256 thr; wave = 16-row strip x 64 cols; A direct from h1 (L2),
// B SPLIT hi/lo bf16 in LDS (fp32-equivalent Wv precision -> gate argmax safe),
// depth-2 prefetch, raw barriers.
__global__ __launch_bounds__(256) void k_vproj(
        const u16* __restrict__ h1, const float* __restrict__ Wv,
        const float* __restrict__ bv, float* __restrict__ vws) {
    __shared__ __align__(16) u16 Bh[64 * 72];   // hi part
    __shared__ __align__(16) u16 Bl[64 * 72];   // lo part
    int m0 = blockIdx.x * 64;
    int tid = threadIdx.x, lane = tid & 63, wid = tid >> 6;
    int bn = tid & 63, bkg = tid >> 6;
    int lr = lane & 15, q = lane >> 4;
    int row = m0 + wid * 16 + lr;
    if (row >= T_TOK) row = T_TOK - 1;       // garbage rows, never stored
    const u16* ap = h1 + (size_t)row * DM;

    f32x4_t acc[4];
#pragma unroll
    for (int ni = 0; ni < 4; ni++) acc[ni] = (f32x4_t){0.f, 0.f, 0.f, 0.f};

    bf16x8_t aP[2], aQ[2];
    float bP[16], bQ[16];

#define G_LOAD_A(SA, KT) { \
    int k0_ = (KT) * 64; \
    SA[0] = *(const bf16x8_t*)&ap[k0_ + q * 8]; \
    SA[1] = *(const bf16x8_t*)&ap[k0_ + 32 + q * 8]; \
}
#define G_LOAD_B(SB, KT) { \
    const float* bp_ = Wv + (size_t)((KT) * 64 + bkg * 16) * HD + bn; \
    _Pragma("unroll") \
    for (int kk = 0; kk < 16; kk++) SB[kk] = bp_[(size_t)kk * HD]; \
}
#define STORE_B(SB) { \
    bf16x8_t h0_, h1_, l0_, l1_; \
    _Pragma("unroll") \
    for (int kk = 0; kk < 8; kk++) { \
        float w0 = SB[kk], w1 = SB[kk + 8]; \
        u16 hh0 = f2bf(w0), hh1 = f2bf(w1); \
        h0_[kk] = (short)hh0; h1_[kk] = (short)hh1; \
        l0_[kk] = (short)f2bf(w0 - bf2f(hh0)); \
        l1_[kk] = (short)f2bf(w1 - bf2f(hh1)); \
    } \
    *(bf16x8_t*)&Bh[bn * 72 + bkg * 16] = h0_; \
    *(bf16x8_t*)&Bh[bn * 72 + bkg * 16 + 8] = h1_; \
    *(bf16x8_t*)&Bl[bn * 72 + bkg * 16] = l0_; \
    *(bf16x8_t*)&Bl[bn * 72 + bkg * 16 + 8] = l1_; \
}
#define MFMA_TILE(SA) { \
    _Pragma("unroll") \
    for (int s = 0; s < 2; s++) { \
        bf16x8_t bh_[4], bl_[4]; \
        _Pragma("unroll") \
        for (int ni = 0; ni < 4; ni++) { \
            bh_[ni] = *(const bf16x8_t*)&Bh[(ni * 16 + lr) * 72 + s * 32 + q * 8]; \
            bl_[ni] = *(const bf16x8_t*)&Bl[(ni * 16 + lr) * 72 + s * 32 + q * 8]; \
        } \
        _Pragma("unroll") \
        for (int ni = 0; ni < 4; ni++) { \
            acc[ni] = __builtin_amdgcn_mfma_f32_16x16x32_bf16( \
                SA[s], bh_[ni], acc[ni], 0, 0, 0); \
            acc[ni] = __builtin_amdgcn_mfma_f32_16x16x32_bf16( \
                SA[s], bl_[ni], acc[ni], 0, 0, 0); \
        } \
    } \
}
#define PHASE(SA, SB, PKT) { \
    SFENCE(); RAW_BAR(); SFENCE(); \
    STORE_B(SB) \
    asm volatile("s_waitcnt lgkmcnt(0)" ::: "memory"); \
    SFENCE(); RAW_BAR(); SFENCE(); \
    if ((PKT) < 12) G_LOAD_B(SB, PKT) \
    MFMA_TILE(SA) \
    if ((PKT) < 12) G_LOAD_A(SA, PKT) \
}

    G_LOAD_A(aP, 0) G_LOAD_B(bP, 0)
    G_LOAD_A(aQ, 1) G_LOAD_B(bQ, 1)
    for (int kt = 0; kt < 12; kt += 2) {
        PHASE(aP, bP, kt + 2)
        PHASE(aQ, bQ, kt + 3)
    }
#undef G_LOAD_A
#undef G_LOAD_B
#undef STORE_B
#undef MFMA_TILE
#undef PHASE

#pragma unroll
    for (int ni = 0; ni < 4; ni++) {
        float bb = bv[ni * 16 + lr];
#pragma unroll
        for (int r = 0; r < 4; r++) {
            int i = m0 + wid * 16 + q * 4 + r;
            if (i < T_TOK) vws[(size_t)i * HD + ni * 16 + lr] = acc[ni][r] + bb;
        }
    }
}

// ---------------- K3: x2 = x + tile(v); LN2 -> h2; gate; out init (1 wave/token) ----------------
__global__ __launch_bounds__(64) void k_gate(
        const float* __restrict__ x, const float* __restrict__ vws,
        const float* __restrict__ g2, const float* __restrict__ b2g,
        const float* __restrict__ Wg, const float* __restrict__ bg,
        const float* __restrict__ b2moe,
        u16* __restrict__ h2, float* __restrict__ out,
        int* __restrict__ cnt, int* __restrict__ buck) {
    int t = blockIdx.x, lane = threadIdx.x;
    int sl = lane & 15;
    const float* xp = x + (size_t)t * DM;
    f32x4_t xv[3];
    // col c = 4*lane + 256*i + m -> v[c & 63] = v[4*sl + m]
    f32x4_t vv = *(const f32x4_t*)&vws[(size_t)t * HD + 4 * sl];
    float s2 = 0.0f;
#pragma unroll
    for (int i = 0; i < 3; i++) {
        xv[i] = *(const f32x4_t*)&xp[4 * lane + 256 * i];
#pragma unroll
        for (int m = 0; m < 4; m++) { xv[i][m] += vv[m]; s2 += xv[i][m]; }
    }
#pragma unroll
    for (int m = 1; m < 64; m <<= 1) s2 += __shfl_xor(s2, m);
    float mu2 = s2 * (1.0f / DM);
    float vs2 = 0.0f;
#pragma unroll
    for (int i = 0; i < 3; i++)
#pragma unroll
        for (int m = 0; m < 4; m++) { float d = xv[i][m] - mu2; vs2 += d * d; }
#pragma unroll
    for (int m = 1; m < 64; m <<= 1) vs2 += __shfl_xor(vs2, m);
    float rs2 = rsqrtf(vs2 * (1.0f / DM) + 1e-5f);

    float le[NE];
#pragma unroll
    for (int e = 0; e < NE; e++) le[e] = 0.0f;
    u16* h2p = h2 + (size_t)t * DM;
#pragma unroll
    for (int i = 0; i < 3; i++) {
        int c = 4 * lane + 256 * i;
        f32x4_t gg = *(const f32x4_t*)&g2[c];
        f32x4_t bb = *(const f32x4_t*)&b2g[c];
        float h[4];
        u16x4_t hb;
#pragma unroll
        for (int m = 0; m < 4; m++) {
            h[m] = (xv[i][m] - mu2) * rs2 * gg[m] + bb[m];
            hb[m] = f2bf(h[m]);
        }
        *(u16x4_t*)&h2p[c] = hb;   // 8B coalesced
        // gate: rows c..c+3 of Wg[768][8] are 128B contiguous per lane
#pragma unroll
        for (int m = 0; m < 4; m++) {
            f32x4_t w0 = *(const f32x4_t*)&Wg[(size_t)(c + m) * NE];
            f32x4_t w1 = *(const f32x4_t*)&Wg[(size_t)(c + m) * NE + 4];
            le[0] += h[m] * w0[0]; le[1] += h[m] * w0[1];
            le[2] += h[m] * w0[2]; le[3] += h[m] * w0[3];
            le[4] += h[m] * w1[0]; le[5] += h[m] * w1[1];
            le[6] += h[m] * w1[2]; le[7] += h[m] * w1[3];
        }
    }
#pragma unroll
    for (int e = 0; e < NE; e++) {
#pragma unroll
        for (int m = 1; m < 64; m <<= 1) le[e] += __shfl_xor(le[e], m);
    }
    // all lanes hold bitwise-identical le[] (butterfly) -> uniform argmax
    float best = le[0] + bg[0]; int be = 0;
#pragma unroll
    for (int e = 1; e < NE; e++) {
        float qv = le[e] + bg[e];
        if (qv > best) { best = qv; be = e; }   // strict > == first-max (jnp.argmax)
    }
    if (lane == 0) {
        int pos = atomicAdd(&cnt[be], 1);
        buck[be * T_TOK + pos] = t;
    }
    // out init: x2 + b2[be]  (gemm2 atomicAdds the MoE matmul on top)
    float* op = out + (size_t)t * DM;
    const float* bp = b2moe + (size_t)be * DM;
#pragma unroll
    for (int i = 0; i < 3; i++) {
        int c = 4 * lane + 256 * i;
        f32x4_t bbv = *(const f32x4_t*)&bp[c];
        f32x4_t o;
#pragma unroll
        for (int m = 0; m < 4; m++) o[m] = xv[i][m] + bbv[m];
        *(f32x4_t*)&op[c] = o;
    }
}

// ---------------- K4: grouped GEMM1 + gelu: hmid = gelu(h2 @ W1[e] + b1[e]) ----------------
// BM=64, BN=64, BK=64; 4 waves, wave = 16-row strip x 64 cols; A direct->regs.
__global__ __launch_bounds__(256, 4) void k_moe_gemm1(
        const u16* __restrict__ h2, const float* __restrict__ W1,
        const float* __restrict__ b1, const int* __restrict__ cnt,
        const int* __restrict__ buck, u16* __restrict__ hmid) {
    int nt = blockIdx.x, e = blockIdx.y, mt = blockIdx.z;
    int cnte = cnt[e];
    int m0 = mt * 64;
    if (m0 >= cnte) return;
    int n0 = nt * 64;
    const float* W1e = W1 + (size_t)e * DM * FF;
    __shared__ __align__(16) u16 Bs[64 * 72];    // 9 KB, [n][k]
    int tid = threadIdx.x, lane = tid & 63, wid = tid >> 6;
    int bn = tid & 63, bkg = tid >> 6;
    int lr = lane & 15, q = lane >> 4;

    int arow = m0 + wid * 16 + lr;
    if (arow >= cnte) arow = cnte - 1;       // garbage rows, never stored
    const u16* ap = h2 + (size_t)buck[e * T_TOK + arow] * DM;

    f32x4_t acc[4];
#pragma unroll
    for (int ni = 0; ni < 4; ni++) acc[ni] = (f32x4_t){0.f, 0.f, 0.f, 0.f};

    bf16x8_t aP[2], aQ[2];
    float bP[16], bQ[16];

#define G_LOAD_A(SA, KT) { \
    int k0_ = (KT) * 64; \
    SA[0] = *(const bf16x8_t*)&ap[k0_ + q * 8]; \
    SA[1] = *(const bf16x8_t*)&ap[k0_ + 32 + q * 8]; \
}
#define G_LOAD_B(SB, KT) { \
    const float* bp_ = W1e + (size_t)((KT) * 64 + bkg * 16) * FF + n0 + bn; \
    _Pragma("unroll") \
    for (int kk = 0; kk < 16; kk++) SB[kk] = bp_[(size_t)kk * FF]; \
}
#define STORE_B(SB) { \
    bf16x8_t p0_, p1_; \
    _Pragma("unroll") \
    for (int kk = 0; kk < 8; kk++) { \
        p0_[kk] = (short)f2bf(SB[kk]); \
        p1_[kk] = (short)f2bf(SB[kk + 8]); \
    } \
    *(bf16x8_t*)&Bs[bn * 72 + bkg * 16] = p0_; \
    *(bf16x8_t*)&Bs[bn * 72 + bkg * 16 + 8] = p1_; \
}
#define MFMA_TILE(SA) { \
    _Pragma("unroll") \
    for (int s = 0; s < 2; s++) { \
        bf16x8_t bfr[4]; \
        _Pragma("unroll") \
        for (int ni = 0; ni < 4; ni++) \
            bfr[ni] = *(const bf16x8_t*)&Bs[(ni * 16 + lr) * 72 + s * 32 + q * 8]; \
        _Pragma("unroll") \
        for (int ni = 0; ni < 4; ni++) \
            acc[ni] = __builtin_amdgcn_mfma_f32_16x16x32_bf16( \
                SA[s], bfr[ni], acc[ni], 0, 0, 0); \
    } \
}
#define PHASE(SA, SB, PKT) { \
    SFENCE(); RAW_BAR(); SFENCE(); \
    STORE_B(SB) \
    asm volatile("s_waitcnt lgkmcnt(0)" ::: "memory"); \
    SFENCE(); RAW_BAR(); SFENCE(); \
    if ((PKT) < 12) G_LOAD_B(SB, PKT) \
    MFMA_TILE(SA) \
    if ((PKT) < 12) G_LOAD_A(SA, PKT) \
}

    G_LOAD_A(aP, 0) G_LOAD_B(bP, 0)
    G_LOAD_A(aQ, 1) G_LOAD_B(bQ, 1)
    for (int kt = 0; kt < 12; kt += 2) {
        PHASE(aP, bP, kt + 2)
        PHASE(aQ, bQ, kt + 3)
    }
#undef G_LOAD_A
#undef G_LOAD_B
#undef STORE_B
#undef MFMA_TILE
#undef PHASE

    // epilogue: bias + gelu, scatter by token id
    float bias[4];
#pragma unroll
    for (int ni = 0; ni < 4; ni++) bias[ni] = b1[(size_t)e * FF + n0 + ni * 16 + lr];
#pragma unroll
    for (int r = 0; r < 4; r++) {
        int i = m0 + wid * 16 + q * 4 + r;
        if (i < cnte) {
            int t = buck[e * T_TOK + i];
            size_t base = (size_t)t * FF + n0;
#pragma unroll
            for (int ni = 0; ni < 4; ni++)
                hmid[base + ni * 16 + lr] = f2bf(gelu_f(acc[ni][r] + bias[ni]));
        }
    }
}

// ---------------- K5: grouped GEMM2 split-K x4: out += hmid @ W2[e] ----------------
// BM=64, BN=64, BK=64, K-chunk = FF/4 = 768. z = mt*4 + kc. A direct->regs.
__global__ __launch_bounds__(256, 4) void k_moe_gemm2(
        const u16* __restrict__ hmid, const float* __restrict__ W2,
        const int* __restrict__ cnt, const int* __restrict__ buck,
        float* __restrict__ out) {
    int nt = blockIdx.x, e = blockIdx.y, z = blockIdx.z;
    int kc = z & 3, mt = z >> 2;
    int cnte = cnt[e];
    int m0 = mt * 64;
    if (m0 >= cnte) return;
    int n0 = nt * 64;
    int kbase = kc * (FF / 4);
    const float* W2e = W2 + (size_t)e * FF * DM;
    __shared__ __align__(16) u16 Bs[64 * 72];
    int tid = threadIdx.x, lane = tid & 63, wid = tid >> 6;
    int bn = tid & 63, bkg = tid >> 6;
    int lr = lane & 15, q = lane >> 4;

    int arow = m0 + wid * 16 + lr;
    if (arow >= cnte) arow = cnte - 1;       // garbage rows, never stored
    const u16* ap = hmid + (size_t)buck[e * T_TOK + arow] * FF + kbase;

    f32x4_t acc[4];
#pragma unroll
    for (int ni = 0; ni < 4; ni++) acc[ni] = (f32x4_t){0.f, 0.f, 0.f, 0.f};

    bf16x8_t aP[2], aQ[2];
    float bP[16], bQ[16];

#define G_LOAD_A(SA, KT) { \
    int k0_ = (KT) * 64; \
    SA[0] = *(const bf16x8_t*)&ap[k0_ + q * 8]; \
    SA[1] = *(const bf16x8_t*)&ap[k0_ + 32 + q * 8]; \
}
#define G_LOAD_B(SB, KT) { \
    const float* bp_ = W2e + (size_t)(kbase + (KT) * 64 + bkg * 16) * DM + n0 + bn; \
    _Pragma("unroll") \
    for (int kk = 0; kk < 16; kk++) SB[kk] = bp_[(size_t)kk * DM]; \
}
#define STORE_B(SB) { \
    bf16x8_t p0_, p1_; \
    _Pragma("unroll") \
    for (int kk = 0; kk < 8; kk++) { \
        p0_[kk] = (short)f2bf(SB[kk]); \
        p1_[kk] = (short)f2bf(SB[kk + 8]); \
    } \
    *(bf16x8_t*)&Bs[bn * 72 + bkg * 16] = p0_; \
    *(bf16x8_t*)&Bs[bn * 72 + bkg * 16 + 8] = p1_; \
}
#define MFMA_TILE(SA) { \
    _Pragma("unroll") \
    for (int s = 0; s < 2; s++) { \
        bf16x8_t bfr[4]; \
        _Pragma("unroll") \
        for (int ni = 0; ni < 4; ni++) \
            bfr[ni] = *(const bf16x8_t*)&Bs[(ni * 16 + lr) * 72 + s * 32 + q * 8]; \
        _Pragma("unroll") \
        for (int ni = 0; ni < 4; ni++) \
            acc[ni] = __builtin_amdgcn_mfma_f32_16x16x32_bf16( \
                SA[s], bfr[ni], acc[ni], 0, 0, 0); \
    } \
}
#define PHASE(SA, SB, PKT) { \
    SFENCE(); RAW_BAR(); SFENCE(); \
    STORE_B(SB) \
    asm volatile("s_waitcnt lgkmcnt(0)" ::: "memory"); \
    SFENCE(); RAW_BAR(); SFENCE(); \
    if ((PKT) < 12) G_LOAD_B(SB, PKT) \
    MFMA_TILE(SA) \
    if ((PKT) < 12) G_LOAD_A(SA, PKT) \
}

    G_LOAD_A(aP, 0) G_LOAD_B(bP, 0)
    G_LOAD_A(aQ, 1) G_LOAD_B(bQ, 1)
    for (int kt = 0; kt < 12; kt += 2) {
        PHASE(aP, bP, kt + 2)
        PHASE(aQ, bQ, kt + 3)
    }
#undef G_LOAD_A
#undef G_LOAD_B
#undef STORE_B
#undef MFMA_TILE
#undef PHASE

    // epilogue: atomicAdd partials into out (out pre-initialized with x2 + b2[e])
#pragma unroll
    for (int r = 0; r < 4; r++) {
        int i = m0 + wid * 16 + q * 4 + r;
        if (i < cnte) {
            int t = buck[e * T_TOK + i];
            size_t base = (size_t)t * DM + n0;
#pragma unroll
            for (int ni = 0; ni < 4; ni++)
                atomicAdd(&out[base + ni * 16 + lr], acc[ni][r]);
        }
    }
}

extern "C" void kernel_launch(void* const* d_in, const int* in_sizes, int n_in,
                              void* d_out, int out_size, void* d_ws, size_t ws_size,
                              hipStream_t stream) {
    const float* x    = (const float*)d_in[0];
    const float* ln1g = (const float*)d_in[1];
    const float* ln1b = (const float*)d_in[2];
    // d_in[3..6] = Wq,bq,Wk,bk: dead code
    const float* Wv   = (const float*)d_in[7];
    const float* bv   = (const float*)d_in[8];
    const float* ln2g = (const float*)d_in[9];
    const float* ln2b = (const float*)d_in[10];
    const float* Wg   = (const float*)d_in[11];
    const float* bg   = (const float*)d_in[12];
    const float* W1   = (const float*)d_in[13];
    const float* b1   = (const float*)d_in[14];
    const float* W2   = (const float*)d_in[15];
    const float* b2   = (const float*)d_in[16];

    char* ws = (char*)d_ws;
    int*   cnt  = (int*)(ws + OFF_CNT);
    int*   buck = (int*)(ws + OFF_BUCK);
    float* vws  = (float*)(ws + OFF_V);
    u16*   h1   = (u16*)(ws + OFF_H1);
    u16*   h2   = (u16*)(ws + OFF_H2);
    u16*   hmid = (u16*)(ws + OFF_HMID);
    float* out  = (float*)d_out;

    hipMemsetAsync(cnt, 0, NE * sizeof(int), stream);
    k_ln1<<<T_TOK, 64, 0, stream>>>(x, ln1g, ln1b, h1);
    k_vproj<<<(T_TOK + 63) / 64, 256, 0, stream>>>(h1, Wv, bv, vws);
    k_gate<<<T_TOK, 64, 0, stream>>>(x, vws, ln2g, ln2b, Wg, bg, b2,
                                     h2, out, cnt, buck);
    k_moe_gemm1<<<dim3(FF / 64, NE, 25), 256, 0, stream>>>(h2, W1, b1, cnt, buck, hmid);
    k_moe_gemm2<<<dim3(DM / 64, NE, 100), 256, 0, stream>>>(hmid, W2, cnt, buck, out);
}

// Round 7
// 284.353 us; speedup vs baseline: 1.0386x; 1.0386x over previous
//
#include <hip/hip_runtime.h>
#include <hip/hip_bf16.h>

// TransformerBlock: B=8,S=196,D=768,H=12,HD=64,E=8,FF=3072. T = B*S = 1568 tokens.
//
// Exact simplifications:
//  - attention: k,v broadcast across heads -> logits constant over softmax axis
//    -> softmax uniform -> attn_out = tile(v). Wq/bq/Wk/bk/RoPE are dead code.
//  - MoE top-1 = argmax of gating logits (softmax monotone).
//
// R8 structure:
//  - R7 post-mortem: BM=64 quadrupled W2 streaming (FETCH 86->128MB) and lost
//    net despite higher occupancy/BW. R8 combines the counter-validated parts:
//    BM=128 (min B re-read, L3 absorbs 2nd pass) + A-direct-to-regs + 9KB LDS
//    (R6's occupancy/BW gain) + dwordx2 B loads (8 vmem instr/thread/k-tile,
//    512B per wave-instr). Wave = 32-row strip, acc[2][4] (R4-proven mapping).
//  - Depth-2 register prefetch (P/Q sets), raw s_barrier (no vmcnt drain).
//  - k_vproj keeps split-precision Wv (hi+lo bf16) -- gate argmax needs
//    fp32-accurate v (R6 failure).
//  - GEMM2 split-K x4 atomicAdds onto out pre-initialized with x2 + b2[expert].

typedef unsigned short u16;
typedef short bf16x8_t __attribute__((ext_vector_type(8)));
typedef unsigned short u16x4_t __attribute__((ext_vector_type(4)));
typedef float f32x4_t  __attribute__((ext_vector_type(4)));
typedef float f32x2_t  __attribute__((ext_vector_type(2)));

#define T_TOK 1568
#define DM 768
#define HD 64
#define FF 3072
#define NE 8

// workspace layout (16B-aligned offsets; ~14.9 MB total)
#define OFF_CNT   0
#define OFF_BUCK  256
#define OFF_V     (OFF_BUCK + NE*T_TOK*4)
#define OFF_H1    (OFF_V + T_TOK*HD*4)
#define OFF_H2    (OFF_H1 + T_TOK*DM*2)
#define OFF_HMID  (OFF_H2 + T_TOK*DM*2)

__device__ __forceinline__ u16 f2bf(float f) {  // RNE via HW cvt
    return __builtin_bit_cast(u16, __float2bfloat16(f));
}
__device__ __forceinline__ float bf2f(u16 h) {
    unsigned u = ((unsigned)h) << 16;
    return __builtin_bit_cast(float, u);
}
__device__ __forceinline__ float gelu_f(float x) {
    return 0.5f * x * (1.0f + erff(x * 0.70710678118654752440f));
}

#define SFENCE() __builtin_amdgcn_sched_barrier(0)
#define RAW_BAR() __builtin_amdgcn_s_barrier()

// ---------------- K1: LN1 per token -> h1 (bf16), 1 wave/token ----------------
__global__ __launch_bounds__(64) void k_ln1(const float* __restrict__ x,
                                            const float* __restrict__ g1,
                                            const float* __restrict__ b1,
                                            u16* __restrict__ h1) {
    int t = blockIdx.x, lane = threadIdx.x;
    const float* xp = x + (size_t)t * DM;
    f32x4_t xv[3];
    float s = 0.0f;
#pragma unroll
    for (int i = 0; i < 3; i++) {
        xv[i] = *(const f32x4_t*)&xp[4 * lane + 256 * i];
        s += xv[i][0] + xv[i][1] + xv[i][2] + xv[i][3];
    }
#pragma unroll
    for (int m = 1; m < 64; m <<= 1) s += __shfl_xor(s, m);
    float mu = s * (1.0f / DM);
    float vs = 0.0f;
#pragma unroll
    for (int i = 0; i < 3; i++)
#pragma unroll
        for (int m = 0; m < 4; m++) { float d = xv[i][m] - mu; vs += d * d; }
#pragma unroll
    for (int m = 1; m < 64; m <<= 1) vs += __shfl_xor(vs, m);
    float rs = rsqrtf(vs * (1.0f / DM) + 1e-5f);
    u16* hp = h1 + (size_t)t * DM;
#pragma unroll
    for (int i = 0; i < 3; i++) {
        int c = 4 * lane + 256 * i;
        f32x4_t gg = *(const f32x4_t*)&g1[c];
        f32x4_t bb = *(const f32x4_t*)&b1[c];
        u16x4_t hb;
#pragma unroll
        for (int m = 0; m < 4; m++) hb[m] = f2bf((xv[i][m] - mu) * rs * gg[m] + bb[m]);
        *(u16x4_t*)&hp[c] = hb;
    }
}

// ---------------- K2: vproj GEMM: v = h1[1568,768] @ Wv[768,64] + bv ----------------
// 25 blocks x 256 thr; wave = 16-row strip x 64 cols; A direct from h1 (L2),
// B SPLIT hi/lo bf16 in LDS (fp32-equivalent Wv precision -> gate argmax safe),
// depth-2 prefetch, raw barriers.
__global__ __launch_bounds__(256) void k_vproj(
        const u16* __restrict__ h1, const float* __restrict__ Wv,
        const float* __restrict__ bv, float* __restrict__ vws) {
    __shared__ __align__(16) u16 Bh[64 * 72];   // hi part
    __shared__ __align__(16) u16 Bl[64 * 72];   // lo part
    int m0 = blockIdx.x * 64;
    int tid = threadIdx.x, lane = tid & 63, wid = tid >> 6;
    int bn = tid & 63, bkg = tid >> 6;
    int lr = lane & 15, q = lane >> 4;
    int row = m0 + wid * 16 + lr;
    if (row >= T_TOK) row = T_TOK - 1;       // garbage rows, never stored
    const u16* ap = h1 + (size_t)row * DM;

    f32x4_t acc[4];
#pragma unroll
    for (int ni = 0; ni < 4; ni++) acc[ni] = (f32x4_t){0.f, 0.f, 0.f, 0.f};

    bf16x8_t aP[2], aQ[2];
    float bP[16], bQ[16];

#define G_LOAD_A(SA, KT) { \
    int k0_ = (KT) * 64; \
    SA[0] = *(const bf16x8_t*)&ap[k0_ + q * 8]; \
    SA[1] = *(const bf16x8_t*)&ap[k0_ + 32 + q * 8]; \
}
#define G_LOAD_B(SB, KT) { \
    const float* bp_ = Wv + (size_t)((KT) * 64 + bkg * 16) * HD + bn; \
    _Pragma("unroll") \
    for (int kk = 0; kk < 16; kk++) SB[kk] = bp_[(size_t)kk * HD]; \
}
#define STORE_B(SB) { \
    bf16x8_t h0_, h1_, l0_, l1_; \
    _Pragma("unroll") \
    for (int kk = 0; kk < 8; kk++) { \
        float w0 = SB[kk], w1 = SB[kk + 8]; \
        u16 hh0 = f2bf(w0), hh1 = f2bf(w1); \
        h0_[kk] = (short)hh0; h1_[kk] = (short)hh1; \
        l0_[kk] = (short)f2bf(w0 - bf2f(hh0)); \
        l1_[kk] = (short)f2bf(w1 - bf2f(hh1)); \
    } \
    *(bf16x8_t*)&Bh[bn * 72 + bkg * 16] = h0_; \
    *(bf16x8_t*)&Bh[bn * 72 + bkg * 16 + 8] = h1_; \
    *(bf16x8_t*)&Bl[bn * 72 + bkg * 16] = l0_; \
    *(bf16x8_t*)&Bl[bn * 72 + bkg * 16 + 8] = l1_; \
}
#define MFMA_TILE(SA) { \
    _Pragma("unroll") \
    for (int s = 0; s < 2; s++) { \
        bf16x8_t bh_[4], bl_[4]; \
        _Pragma("unroll") \
        for (int ni = 0; ni < 4; ni++) { \
            bh_[ni] = *(const bf16x8_t*)&Bh[(ni * 16 + lr) * 72 + s * 32 + q * 8]; \
            bl_[ni] = *(const bf16x8_t*)&Bl[(ni * 16 + lr) * 72 + s * 32 + q * 8]; \
        } \
        _Pragma("unroll") \
        for (int ni = 0; ni < 4; ni++) { \
            acc[ni] = __builtin_amdgcn_mfma_f32_16x16x32_bf16( \
                SA[s], bh_[ni], acc[ni], 0, 0, 0); \
            acc[ni] = __builtin_amdgcn_mfma_f32_16x16x32_bf16( \
                SA[s], bl_[ni], acc[ni], 0, 0, 0); \
        } \
    } \
}
#define PHASE(SA, SB, PKT) { \
    SFENCE(); RAW_BAR(); SFENCE(); \
    STORE_B(SB) \
    asm volatile("s_waitcnt lgkmcnt(0)" ::: "memory"); \
    SFENCE(); RAW_BAR(); SFENCE(); \
    if ((PKT) < 12) G_LOAD_B(SB, PKT) \
    MFMA_TILE(SA) \
    if ((PKT) < 12) G_LOAD_A(SA, PKT) \
}

    G_LOAD_A(aP, 0) G_LOAD_B(bP, 0)
    G_LOAD_A(aQ, 1) G_LOAD_B(bQ, 1)
    for (int kt = 0; kt < 12; kt += 2) {
        PHASE(aP, bP, kt + 2)
        PHASE(aQ, bQ, kt + 3)
    }
#undef G_LOAD_A
#undef G_LOAD_B
#undef STORE_B
#undef MFMA_TILE
#undef PHASE

#pragma unroll
    for (int ni = 0; ni < 4; ni++) {
        float bb = bv[ni * 16 + lr];
#pragma unroll
        for (int r = 0; r < 4; r++) {
            int i = m0 + wid * 16 + q * 4 + r;
            if (i < T_TOK) vws[(size_t)i * HD + ni * 16 + lr] = acc[ni][r] + bb;
        }
    }
}

// ---------------- K3: x2 = x + tile(v); LN2 -> h2; gate; out init (1 wave/token) ----------------
__global__ __launch_bounds__(64) void k_gate(
        const float* __restrict__ x, const float* __restrict__ vws,
        const float* __restrict__ g2, const float* __restrict__ b2g,
        const float* __restrict__ Wg, const float* __restrict__ bg,
        const float* __restrict__ b2moe,
        u16* __restrict__ h2, float* __restrict__ out,
        int* __restrict__ cnt, int* __restrict__ buck) {
    int t = blockIdx.x, lane = threadIdx.x;
    int sl = lane & 15;
    const float* xp = x + (size_t)t * DM;
    f32x4_t xv[3];
    // col c = 4*lane + 256*i + m -> v[c & 63] = v[4*sl + m]
    f32x4_t vv = *(const f32x4_t*)&vws[(size_t)t * HD + 4 * sl];
    float s2 = 0.0f;
#pragma unroll
    for (int i = 0; i < 3; i++) {
        xv[i] = *(const f32x4_t*)&xp[4 * lane + 256 * i];
#pragma unroll
        for (int m = 0; m < 4; m++) { xv[i][m] += vv[m]; s2 += xv[i][m]; }
    }
#pragma unroll
    for (int m = 1; m < 64; m <<= 1) s2 += __shfl_xor(s2, m);
    float mu2 = s2 * (1.0f / DM);
    float vs2 = 0.0f;
#pragma unroll
    for (int i = 0; i < 3; i++)
#pragma unroll
        for (int m = 0; m < 4; m++) { float d = xv[i][m] - mu2; vs2 += d * d; }
#pragma unroll
    for (int m = 1; m < 64; m <<= 1) vs2 += __shfl_xor(vs2, m);
    float rs2 = rsqrtf(vs2 * (1.0f / DM) + 1e-5f);

    float le[NE];
#pragma unroll
    for (int e = 0; e < NE; e++) le[e] = 0.0f;
    u16* h2p = h2 + (size_t)t * DM;
#pragma unroll
    for (int i = 0; i < 3; i++) {
        int c = 4 * lane + 256 * i;
        f32x4_t gg = *(const f32x4_t*)&g2[c];
        f32x4_t bb = *(const f32x4_t*)&b2g[c];
        float h[4];
        u16x4_t hb;
#pragma unroll
        for (int m = 0; m < 4; m++) {
            h[m] = (xv[i][m] - mu2) * rs2 * gg[m] + bb[m];
            hb[m] = f2bf(h[m]);
        }
        *(u16x4_t*)&h2p[c] = hb;   // 8B coalesced
        // gate: rows c..c+3 of Wg[768][8] are 128B contiguous per lane
#pragma unroll
        for (int m = 0; m < 4; m++) {
            f32x4_t w0 = *(const f32x4_t*)&Wg[(size_t)(c + m) * NE];
            f32x4_t w1 = *(const f32x4_t*)&Wg[(size_t)(c + m) * NE + 4];
            le[0] += h[m] * w0[0]; le[1] += h[m] * w0[1];
            le[2] += h[m] * w0[2]; le[3] += h[m] * w0[3];
            le[4] += h[m] * w1[0]; le[5] += h[m] * w1[1];
            le[6] += h[m] * w1[2]; le[7] += h[m] * w1[3];
        }
    }
#pragma unroll
    for (int e = 0; e < NE; e++) {
#pragma unroll
        for (int m = 1; m < 64; m <<= 1) le[e] += __shfl_xor(le[e], m);
    }
    // all lanes hold bitwise-identical le[] (butterfly) -> uniform argmax
    float best = le[0] + bg[0]; int be = 0;
#pragma unroll
    for (int e = 1; e < NE; e++) {
        float qv = le[e] + bg[e];
        if (qv > best) { best = qv; be = e; }   // strict > == first-max (jnp.argmax)
    }
    if (lane == 0) {
        int pos = atomicAdd(&cnt[be], 1);
        buck[be * T_TOK + pos] = t;
    }
    // out init: x2 + b2[be]  (gemm2 atomicAdds the MoE matmul on top)
    float* op = out + (size_t)t * DM;
    const float* bp = b2moe + (size_t)be * DM;
#pragma unroll
    for (int i = 0; i < 3; i++) {
        int c = 4 * lane + 256 * i;
        f32x4_t bbv = *(const f32x4_t*)&bp[c];
        f32x4_t o;
#pragma unroll
        for (int m = 0; m < 4; m++) o[m] = xv[i][m] + bbv[m];
        *(f32x4_t*)&op[c] = o;
    }
}

// ---------------- K4: grouped GEMM1 + gelu: hmid = gelu(h2 @ W1[e] + b1[e]) ----------------
// BM=128, BN=64, BK=64; 4 waves, wave = 32-row strip x 64 cols; A direct->regs;
// B loads dwordx2 (n2 = (tid&31)*2, kg = tid>>5); LDS = B only, 9 KB.
__global__ __launch_bounds__(256, 3) void k_moe_gemm1(
        const u16* __restrict__ h2, const float* __restrict__ W1,
        const float* __restrict__ b1, const int* __restrict__ cnt,
        const int* __restrict__ buck, u16* __restrict__ hmid) {
    int nt = blockIdx.x, e = blockIdx.y, mt = blockIdx.z;
    int cnte = cnt[e];
    int m0 = mt * 128;
    if (m0 >= cnte) return;
    int n0 = nt * 64;
    const float* W1e = W1 + (size_t)e * DM * FF;
    __shared__ __align__(16) u16 Bs[64 * 72];    // 9 KB, [n][k]
    int tid = threadIdx.x, lane = tid & 63, wid = tid >> 6;
    int n2 = (tid & 31) * 2, kg = tid >> 5;      // B staging map
    int lr = lane & 15, q = lane >> 4;

    int ar0 = m0 + wid * 32 + lr;
    int ar1 = ar0 + 16;
    if (ar0 >= cnte) ar0 = cnte - 1;             // garbage rows, never stored
    if (ar1 >= cnte) ar1 = cnte - 1;
    const u16* ap0 = h2 + (size_t)buck[e * T_TOK + ar0] * DM;
    const u16* ap1 = h2 + (size_t)buck[e * T_TOK + ar1] * DM;

    f32x4_t acc[2][4];
#pragma unroll
    for (int mi = 0; mi < 2; mi++)
#pragma unroll
        for (int ni = 0; ni < 4; ni++) acc[mi][ni] = (f32x4_t){0.f, 0.f, 0.f, 0.f};

    bf16x8_t aP[4], aQ[4];   // [s*2+mi]
    float bP[16], bQ[16];    // [c*8+r], c = n2 offset 0/1, r = k within kg*8

#define G_LOAD_A(SA, KT) { \
    int k0_ = (KT) * 64; \
    SA[0] = *(const bf16x8_t*)&ap0[k0_ + q * 8]; \
    SA[1] = *(const bf16x8_t*)&ap1[k0_ + q * 8]; \
    SA[2] = *(const bf16x8_t*)&ap0[k0_ + 32 + q * 8]; \
    SA[3] = *(const bf16x8_t*)&ap1[k0_ + 32 + q * 8]; \
}
#define G_LOAD_B(SB, KT) { \
    const float* bp_ = W1e + (size_t)((KT) * 64 + kg * 8) * FF + n0 + n2; \
    _Pragma("unroll") \
    for (int r = 0; r < 8; r++) { \
        f32x2_t t_ = *(const f32x2_t*)&bp_[(size_t)r * FF]; \
        SB[r] = t_[0]; SB[8 + r] = t_[1]; \
    } \
}
#define STORE_B(SB) { \
    bf16x8_t p0_, p1_; \
    _Pragma("unroll") \
    for (int r = 0; r < 8; r++) { \
        p0_[r] = (short)f2bf(SB[r]); \
        p1_[r] = (short)f2bf(SB[8 + r]); \
    } \
    *(bf16x8_t*)&Bs[n2 * 72 + kg * 8] = p0_; \
    *(bf16x8_t*)&Bs[(n2 + 1) * 72 + kg * 8] = p1_; \
}
#define MFMA_TILE(SA) { \
    _Pragma("unroll") \
    for (int s = 0; s < 2; s++) { \
        bf16x8_t bfr[4]; \
        _Pragma("unroll") \
        for (int ni = 0; ni < 4; ni++) \
            bfr[ni] = *(const bf16x8_t*)&Bs[(ni * 16 + lr) * 72 + s * 32 + q * 8]; \
        _Pragma("unroll") \
        for (int mi = 0; mi < 2; mi++) \
            _Pragma("unroll") \
            for (int ni = 0; ni < 4; ni++) \
                acc[mi][ni] = __builtin_amdgcn_mfma_f32_16x16x32_bf16( \
                    SA[s * 2 + mi], bfr[ni], acc[mi][ni], 0, 0, 0); \
    } \
}
#define PHASE(SA, SB, PKT) { \
    SFENCE(); RAW_BAR(); SFENCE(); \
    STORE_B(SB) \
    asm volatile("s_waitcnt lgkmcnt(0)" ::: "memory"); \
    SFENCE(); RAW_BAR(); SFENCE(); \
    if ((PKT) < 12) G_LOAD_B(SB, PKT) \
    MFMA_TILE(SA) \
    if ((PKT) < 12) G_LOAD_A(SA, PKT) \
}

    G_LOAD_A(aP, 0) G_LOAD_B(bP, 0)
    G_LOAD_A(aQ, 1) G_LOAD_B(bQ, 1)
    for (int kt = 0; kt < 12; kt += 2) {
        PHASE(aP, bP, kt + 2)
        PHASE(aQ, bQ, kt + 3)
    }
#undef G_LOAD_A
#undef G_LOAD_B
#undef STORE_B
#undef MFMA_TILE
#undef PHASE

    // epilogue: bias + gelu, scatter by token id
    float bias[4];
#pragma unroll
    for (int ni = 0; ni < 4; ni++) bias[ni] = b1[(size_t)e * FF + n0 + ni * 16 + lr];
#pragma unroll
    for (int mi = 0; mi < 2; mi++) {
#pragma unroll
        for (int r = 0; r < 4; r++) {
            int i = m0 + wid * 32 + mi * 16 + q * 4 + r;
            if (i < cnte) {
                int t = buck[e * T_TOK + i];
                size_t base = (size_t)t * FF + n0;
#pragma unroll
                for (int ni = 0; ni < 4; ni++)
                    hmid[base + ni * 16 + lr] = f2bf(gelu_f(acc[mi][ni][r] + bias[ni]));
            }
        }
    }
}

// ---------------- K5: grouped GEMM2 split-K x4: out += hmid @ W2[e] ----------------
// BM=128, BN=64, BK=64, K-chunk = FF/4 = 768. z = mt*4 + kc. A direct->regs.
__global__ __launch_bounds__(256, 3) void k_moe_gemm2(
        const u16* __restrict__ hmid, const float* __restrict__ W2,
        const int* __restrict__ cnt, const int* __restrict__ buck,
        float* __restrict__ out) {
    int nt = blockIdx.x, e = blockIdx.y, z = blockIdx.z;
    int kc = z & 3, mt = z >> 2;
    int cnte = cnt[e];
    int m0 = mt * 128;
    if (m0 >= cnte) return;
    int n0 = nt * 64;
    int kbase = kc * (FF / 4);
    const float* W2e = W2 + (size_t)e * FF * DM;
    __shared__ __align__(16) u16 Bs[64 * 72];
    int tid = threadIdx.x, lane = tid & 63, wid = tid >> 6;
    int n2 = (tid & 31) * 2, kg = tid >> 5;
    int lr = lane & 15, q = lane >> 4;

    int ar0 = m0 + wid * 32 + lr;
    int ar1 = ar0 + 16;
    if (ar0 >= cnte) ar0 = cnte - 1;             // garbage rows, never stored
    if (ar1 >= cnte) ar1 = cnte - 1;
    const u16* ap0 = hmid + (size_t)buck[e * T_TOK + ar0] * FF + kbase;
    const u16* ap1 = hmid + (size_t)buck[e * T_TOK + ar1] * FF + kbase;

    f32x4_t acc[2][4];
#pragma unroll
    for (int mi = 0; mi < 2; mi++)
#pragma unroll
        for (int ni = 0; ni < 4; ni++) acc[mi][ni] = (f32x4_t){0.f, 0.f, 0.f, 0.f};

    bf16x8_t aP[4], aQ[4];
    float bP[16], bQ[16];

#define G_LOAD_A(SA, KT) { \
    int k0_ = (KT) * 64; \
    SA[0] = *(const bf16x8_t*)&ap0[k0_ + q * 8]; \
    SA[1] = *(const bf16x8_t*)&ap1[k0_ + q * 8]; \
    SA[2] = *(const bf16x8_t*)&ap0[k0_ + 32 + q * 8]; \
    SA[3] = *(const bf16x8_t*)&ap1[k0_ + 32 + q * 8]; \
}
#define G_LOAD_B(SB, KT) { \
    const float* bp_ = W2e + (size_t)(kbase + (KT) * 64 + kg * 8) * DM + n0 + n2; \
    _Pragma("unroll") \
    for (int r = 0; r < 8; r++) { \
        f32x2_t t_ = *(const f32x2_t*)&bp_[(size_t)r * DM]; \
        SB[r] = t_[0]; SB[8 + r] = t_[1]; \
    } \
}
#define STORE_B(SB) { \
    bf16x8_t p0_, p1_; \
    _Pragma("unroll") \
    for (int r = 0; r < 8; r++) { \
        p0_[r] = (short)f2bf(SB[r]); \
        p1_[r] = (short)f2bf(SB[8 + r]); \
    } \
    *(bf16x8_t*)&Bs[n2 * 72 + kg * 8] = p0_; \
    *(bf16x8_t*)&Bs[(n2 + 1) * 72 + kg * 8] = p1_; \
}
#define MFMA_TILE(SA) { \
    _Pragma("unroll") \
    for (int s = 0; s < 2; s++) { \
        bf16x8_t bfr[4]; \
        _Pragma("unroll") \
        for (int ni = 0; ni < 4; ni++) \
            bfr[ni] = *(const bf16x8_t*)&Bs[(ni * 16 + lr) * 72 + s * 32 + q * 8]; \
        _Pragma("unroll") \
        for (int mi = 0; mi < 2; mi++) \
            _Pragma("unroll") \
            for (int ni = 0; ni < 4; ni++) \
                acc[mi][ni] = __builtin_amdgcn_mfma_f32_16x16x32_bf16( \
                    SA[s * 2 + mi], bfr[ni], acc[mi][ni], 0, 0, 0); \
    } \
}
#define PHASE(SA, SB, PKT) { \
    SFENCE(); RAW_BAR(); SFENCE(); \
    STORE_B(SB) \
    asm volatile("s_waitcnt lgkmcnt(0)" ::: "memory"); \
    SFENCE(); RAW_BAR(); SFENCE(); \
    if ((PKT) < 12) G_LOAD_B(SB, PKT) \
    MFMA_TILE(SA) \
    if ((PKT) < 12) G_LOAD_A(SA, PKT) \
}

    G_LOAD_A(aP, 0) G_LOAD_B(bP, 0)
    G_LOAD_A(aQ, 1) G_LOAD_B(bQ, 1)
    for (int kt = 0; kt < 12; kt += 2) {
        PHASE(aP, bP, kt + 2)
        PHASE(aQ, bQ, kt + 3)
    }
#undef G_LOAD_A
#undef G_LOAD_B
#undef STORE_B
#undef MFMA_TILE
#undef PHASE

    // epilogue: atomicAdd partials into out (out pre-initialized with x2 + b2[e])
#pragma unroll
    for (int mi = 0; mi < 2; mi++) {
#pragma unroll
        for (int r = 0; r < 4; r++) {
            int i = m0 + wid * 32 + mi * 16 + q * 4 + r;
            if (i < cnte) {
                int t = buck[e * T_TOK + i];
                size_t base = (size_t)t * DM + n0;
#pragma unroll
                for (int ni = 0; ni < 4; ni++)
                    atomicAdd(&out[base + ni * 16 + lr], acc[mi][ni][r]);
            }
        }
    }
}

extern "C" void kernel_launch(void* const* d_in, const int* in_sizes, int n_in,
                              void* d_out, int out_size, void* d_ws, size_t ws_size,
                              hipStream_t stream) {
    const float* x    = (const float*)d_in[0];
    const float* ln1g = (const float*)d_in[1];
    const float* ln1b = (const float*)d_in[2];
    // d_in[3..6] = Wq,bq,Wk,bk: dead code
    const float* Wv   = (const float*)d_in[7];
    const float* bv   = (const float*)d_in[8];
    const float* ln2g = (const float*)d_in[9];
    const float* ln2b = (const float*)d_in[10];
    const float* Wg   = (const float*)d_in[11];
    const float* bg   = (const float*)d_in[12];
    const float* W1   = (const float*)d_in[13];
    const float* b1   = (const float*)d_in[14];
    const float* W2   = (const float*)d_in[15];
    const float* b2   = (const float*)d_in[16];

    char* ws = (char*)d_ws;
    int*   cnt  = (int*)(ws + OFF_CNT);
    int*   buck = (int*)(ws + OFF_BUCK);
    float* vws  = (float*)(ws + OFF_V);
    u16*   h1   = (u16*)(ws + OFF_H1);
    u16*   h2   = (u16*)(ws + OFF_H2);
    u16*   hmid = (u16*)(ws + OFF_HMID);
    float* out  = (float*)d_out;

    hipMemsetAsync(cnt, 0, NE * sizeof(int), stream);
    k_ln1<<<T_TOK, 64, 0, stream>>>(x, ln1g, ln1b, h1);
    k_vproj<<<(T_TOK + 63) / 64, 256, 0, stream>>>(h1, Wv, bv, vws);
    k_gate<<<T_TOK, 64, 0, stream>>>(x, vws, ln2g, ln2b, Wg, bg, b2,
                                     h2, out, cnt, buck);
    k_moe_gemm1<<<dim3(FF / 64, NE, 13), 256, 0, stream>>>(h2, W1, b1, cnt, buck, hmid);
    k_moe_gemm2<<<dim3(DM / 64, NE, 52), 256, 0, stream>>>(hmid, W2, cnt, buck, out);
}